// Round 2
// baseline (2797.346 us; speedup 1.0000x reference)
//
#include <hip/hip_runtime.h>
#include <cstdint>
#include <cstddef>

// ---------------------------------------------------------------------------
// AutoformerEncodeBlock: LN -> q,k,v GEMMs -> FFT autocorrelation top-7 lag
// aggregation -> Wo GEMM (+bias+residual) -> decomp1 (x - movavg25) ->
// FFN (GELU) -> residual -> decomp2 -> out.
// B=8 L=2048 C=1024 H=16 D=64 Hd=4096, fp32 in/out, fp16 MFMA for GEMMs.
// Workspace budget: ~152 MB (q/k/v fp16, FFN chunked x4, x2 lives in d_out).
// ---------------------------------------------------------------------------

typedef _Float16 half8 __attribute__((ext_vector_type(8)));
typedef _Float16 half4 __attribute__((ext_vector_type(4)));
typedef float floatx4 __attribute__((ext_vector_type(4)));

#define PI_F 3.14159265358979323846f

// ---------------------------- small utility kernels ------------------------

__global__ __launch_bounds__(256) void zero_kernel(float* p, int n) {
  int i = blockIdx.x * 256 + threadIdx.x;
  if (i < n) p[i] = 0.f;
}

__global__ __launch_bounds__(256) void cvt_f16_kernel(const float* __restrict__ src,
                                                      _Float16* __restrict__ dst, int n4) {
  int i = blockIdx.x * 256 + threadIdx.x;
  if (i >= n4) return;
  float4 v = ((const float4*)src)[i];
  half4 h = {(_Float16)v.x, (_Float16)v.y, (_Float16)v.z, (_Float16)v.w};
  ((half4*)dst)[i] = h;
}

// --------------------------------- LayerNorm -------------------------------
// one block per row (C=1024, 256 threads * float4)
__global__ __launch_bounds__(256) void ln_kernel(const float* __restrict__ x,
                                                 const float* __restrict__ g,
                                                 const float* __restrict__ b,
                                                 _Float16* __restrict__ xn, int C) {
  int row = blockIdx.x;
  int t = threadIdx.x;
  const float4* xr = (const float4*)(x + (size_t)row * C);
  float4 v = xr[t];
  float s = v.x + v.y + v.z + v.w;
  float s2 = v.x * v.x + v.y * v.y + v.z * v.z + v.w * v.w;
  for (int o = 32; o > 0; o >>= 1) {
    s += __shfl_down(s, o, 64);
    s2 += __shfl_down(s2, o, 64);
  }
  __shared__ float red[8];
  int wave = t >> 6, lane = t & 63;
  if (lane == 0) { red[wave] = s; red[4 + wave] = s2; }
  __syncthreads();
  __shared__ float stats[2];
  if (t == 0) {
    float ts = red[0] + red[1] + red[2] + red[3];
    float ts2 = red[4] + red[5] + red[6] + red[7];
    float mu = ts / (float)C;
    float var = ts2 / (float)C - mu * mu;
    stats[0] = mu;
    stats[1] = 1.0f / sqrtf(var + 1e-5f);
  }
  __syncthreads();
  float mu = stats[0], rs = stats[1];
  float4 gv = ((const float4*)g)[t];
  float4 bv = ((const float4*)b)[t];
  half4 h = {(_Float16)((v.x - mu) * rs * gv.x + bv.x),
             (_Float16)((v.y - mu) * rs * gv.y + bv.y),
             (_Float16)((v.z - mu) * rs * gv.z + bv.z),
             (_Float16)((v.w - mu) * rs * gv.w + bv.w)};
  ((half4*)(xn + (size_t)row * C))[t] = h;
}

// ----------------------------------- GEMM ----------------------------------
// C[M,N] = A[M,K] * Bw[N,K]^T  (both fp16 row-major, K-contiguous)
// 128x128 tile, BK=64, 4 waves 2x2, each wave 4x4 of 16x16x32 MFMA.
// EPI: 0 = plain fp32, 1 = +bias[col]+res fp32, 2 = GELU -> fp16,
//      3 = +res fp32, 4 = plain fp16
template <int EPI>
__global__ __launch_bounds__(256) void gemm_kernel(
    const _Float16* __restrict__ A, const _Float16* __restrict__ Bw,
    int M, int N, int K,
    float* __restrict__ outf, _Float16* __restrict__ outh,
    const float* __restrict__ bias, const float* __restrict__ res) {
  __shared__ _Float16 sA[128 * 64];
  __shared__ _Float16 sB[128 * 64];

  int tid = threadIdx.x;
  int lane = tid & 63;
  int wave = tid >> 6;
  int wm = wave >> 1, wn = wave & 1;
  int ln15 = lane & 15, q4 = lane >> 4;

  size_t m0 = (size_t)blockIdx.y * 128;
  size_t n0 = (size_t)blockIdx.x * 128;

  floatx4 acc[4][4] = {};

  // staging: 1024 16B-chunks per tile; thread handles chunks tid + 256*j
  int row0 = tid >> 3;        // 0..31
  int col16 = tid & 7;        // 16B chunk within a 64-half row
  size_t a_base = (m0 + row0) * (size_t)K + (size_t)(col16 * 8);
  size_t b_base = (n0 + row0) * (size_t)K + (size_t)(col16 * 8);
  int ldsoff0 = row0 * 64 + ((col16 ^ (row0 & 7)) << 3);  // XOR swizzle

  uint4 av[4], bv[4];
  int nk = K >> 6;
#pragma unroll
  for (int j = 0; j < 4; ++j) {
    av[j] = *(const uint4*)(A + a_base + (size_t)(32 * j) * K);
    bv[j] = *(const uint4*)(Bw + b_base + (size_t)(32 * j) * K);
  }

  int sw = ln15 & 7;
  for (int ks = 0; ks < nk; ++ks) {
    __syncthreads();
#pragma unroll
    for (int j = 0; j < 4; ++j) {
      *(uint4*)(sA + ldsoff0 + j * 2048) = av[j];
      *(uint4*)(sB + ldsoff0 + j * 2048) = bv[j];
    }
    __syncthreads();
    if (ks + 1 < nk) {
      size_t k0 = (size_t)(ks + 1) << 6;
#pragma unroll
      for (int j = 0; j < 4; ++j) {
        av[j] = *(const uint4*)(A + a_base + k0 + (size_t)(32 * j) * K);
        bv[j] = *(const uint4*)(Bw + b_base + k0 + (size_t)(32 * j) * K);
      }
    }
#pragma unroll
    for (int kk = 0; kk < 64; kk += 32) {
      int coff = ((((kk >> 3) + q4) ^ sw) << 3);
      half8 af[4], bf[4];
#pragma unroll
      for (int mi = 0; mi < 4; ++mi)
        af[mi] = *(const half8*)(sA + (wm * 64 + mi * 16 + ln15) * 64 + coff);
#pragma unroll
      for (int ni = 0; ni < 4; ++ni)
        bf[ni] = *(const half8*)(sB + (wn * 64 + ni * 16 + ln15) * 64 + coff);
#pragma unroll
      for (int mi = 0; mi < 4; ++mi)
#pragma unroll
        for (int ni = 0; ni < 4; ++ni)
          acc[mi][ni] = __builtin_amdgcn_mfma_f32_16x16x32_f16(af[mi], bf[ni], acc[mi][ni], 0, 0, 0);
    }
  }

  // epilogue: D row = q4*4 + r, col = ln15 within each 16x16 tile
#pragma unroll
  for (int mi = 0; mi < 4; ++mi) {
#pragma unroll
    for (int ni = 0; ni < 4; ++ni) {
      floatx4 a4 = acc[mi][ni];
#pragma unroll
      for (int r = 0; r < 4; ++r) {
        size_t row = m0 + wm * 64 + mi * 16 + q4 * 4 + r;
        size_t col = n0 + wn * 64 + ni * 16 + ln15;
        size_t idx = row * (size_t)N + col;
        float v = a4[r];
        if (EPI == 0) {
          outf[idx] = v;
        } else if (EPI == 1) {
          outf[idx] = v + bias[col] + res[idx];
        } else if (EPI == 2) {
          float ge = 0.5f * v * (1.0f + erff(v * 0.70710678118654752f));
          outh[idx] = (_Float16)ge;
        } else if (EPI == 3) {
          outf[idx] = v + res[idx];
        } else {
          outh[idx] = (_Float16)v;
        }
      }
    }
  }
}

// --------------------- autocorrelation: packed FFT + spectrum --------------
// block = (b, 4 channels). z = q + i*k, 2048-pt radix-2 DIF FFT in LDS
// (bit-reversed output), extract Qf,Kf by hermitian split, accumulate
// S[b][f] += sum_ch Qf*conj(Kf), f = 0..1024, via global fp32 atomics.
__global__ __launch_bounds__(256) void corr_fft_kernel(const _Float16* __restrict__ q,
                                                       const _Float16* __restrict__ k,
                                                       float* __restrict__ S,
                                                       int L, int C) {
  __shared__ float2 Z[4][2048];  // 64 KB
  int cgn = C >> 2;
  int b = blockIdx.x / cgn;
  int c0 = (blockIdx.x % cgn) << 2;
  int tid = threadIdx.x;
  const _Float16* qb = q + (size_t)b * L * C;
  const _Float16* kb = k + (size_t)b * L * C;
  for (int i = tid; i < 4 * 2048; i += 256) {
    int ch = i & 3, l = i >> 2;
    size_t off = (size_t)l * C + c0 + ch;
    Z[ch][l] = make_float2((float)qb[off], (float)kb[off]);
  }
  __syncthreads();
  for (int sh = 10; sh >= 0; --sh) {
    int s = 1 << sh;
    for (int i = tid; i < 4 * 1024; i += 256) {
      int ch = i >> 10;
      int j = i & 1023;
      int t = j & (s - 1);
      int i0 = ((j >> sh) << (sh + 1)) | t;
      int i1 = i0 + s;
      float2 a = Z[ch][i0], bb = Z[ch][i1];
      float2 sum = make_float2(a.x + bb.x, a.y + bb.y);
      float2 d = make_float2(a.x - bb.x, a.y - bb.y);
      float ang = -PI_F * (float)t / (float)s;
      float sn, cs;
      __sincosf(ang, &sn, &cs);
      Z[ch][i0] = sum;
      Z[ch][i1] = make_float2(d.x * cs - d.y * sn, d.x * sn + d.y * cs);
    }
    __syncthreads();
  }
  float* Sb = S + (size_t)b * 1025 * 2;
  for (int f = tid; f <= 1024; f += 256) {
    int rf = __brev((unsigned)f) >> 21;
    int rmf = __brev((unsigned)((2048 - f) & 2047)) >> 21;
    float pr = 0.f, pi = 0.f;
#pragma unroll
    for (int ch = 0; ch < 4; ++ch) {
      float2 zf = Z[ch][rf], zm = Z[ch][rmf];
      float Qr = 0.5f * (zf.x + zm.x), Qi = 0.5f * (zf.y - zm.y);
      float Kr = 0.5f * (zf.y + zm.y), Ki = -0.5f * (zf.x - zm.x);
      pr += Qr * Kr + Qi * Ki;
      pi += Qi * Kr - Qr * Ki;
    }
    atomicAdd(&Sb[2 * f], pr);
    atomicAdd(&Sb[2 * f + 1], pi);
  }
}

// --------------- per-batch: inverse FFT -> mean_corr -> top-7 + softmax ----
__global__ __launch_bounds__(256) void corr_topk_kernel(const float* __restrict__ S,
                                                        int* __restrict__ delays,
                                                        float* __restrict__ alphas,
                                                        int C, int L) {
  __shared__ float2 W[2048];
  __shared__ float mc[2048];
  __shared__ float rv[4];
  __shared__ int ri[4];
  __shared__ float swv[7];
  __shared__ int sdi[7];
  int b = blockIdx.x, tid = threadIdx.x;
  const float* Sb = S + (size_t)b * 1025 * 2;
  // W = conj(S_full): mean_corr = Re(FFT_fwd(conj(S_full)))/(C*L)
  for (int f = tid; f < 2048; f += 256) {
    if (f <= 1024) W[f] = make_float2(Sb[2 * f], -Sb[2 * f + 1]);
    else           W[f] = make_float2(Sb[2 * (2048 - f)], Sb[2 * (2048 - f) + 1]);
  }
  __syncthreads();
  for (int sh = 10; sh >= 0; --sh) {
    int s = 1 << sh;
    for (int j = tid; j < 1024; j += 256) {
      int t = j & (s - 1);
      int i0 = ((j >> sh) << (sh + 1)) | t;
      int i1 = i0 + s;
      float2 a = W[i0], bb = W[i1];
      float2 sum = make_float2(a.x + bb.x, a.y + bb.y);
      float2 d = make_float2(a.x - bb.x, a.y - bb.y);
      float ang = -PI_F * (float)t / (float)s;
      float sn, cs;
      __sincosf(ang, &sn, &cs);
      W[i0] = sum;
      W[i1] = make_float2(d.x * cs - d.y * sn, d.x * sn + d.y * cs);
    }
    __syncthreads();
  }
  float inv = 1.0f / ((float)C * (float)L);
  for (int t = tid; t < 2048; t += 256) mc[t] = W[__brev((unsigned)t) >> 21].x * inv;
  __syncthreads();
  int wv = tid >> 6, lane = tid & 63;
  for (int it = 0; it < 7; ++it) {
    float bvv = -1e30f;
    int bi = 0;
    for (int e = tid * 8; e < tid * 8 + 8; ++e) {
      float v = mc[e];
      if (v > bvv) { bvv = v; bi = e; }
    }
    for (int o = 32; o > 0; o >>= 1) {
      float ov = __shfl_down(bvv, o, 64);
      int oi = __shfl_down(bi, o, 64);
      if (ov > bvv || (ov == bvv && oi < bi)) { bvv = ov; bi = oi; }
    }
    if (lane == 0) { rv[wv] = bvv; ri[wv] = bi; }
    __syncthreads();
    if (tid == 0) {
      float fv = rv[0];
      int fi = ri[0];
      for (int w2 = 1; w2 < 4; ++w2)
        if (rv[w2] > fv || (rv[w2] == fv && ri[w2] < fi)) { fv = rv[w2]; fi = ri[w2]; }
      swv[it] = fv;
      sdi[it] = fi;
      mc[fi] = -1e30f;
    }
    __syncthreads();
  }
  if (tid == 0) {
    float mx = swv[0];
    for (int i = 1; i < 7; ++i) mx = fmaxf(mx, swv[i]);
    float e[7], s = 0.f;
    for (int i = 0; i < 7; ++i) { e[i] = expf(swv[i] - mx); s += e[i]; }
    for (int i = 0; i < 7; ++i) {
      alphas[b * 7 + i] = e[i] / s;
      delays[b * 7 + i] = sdi[i];
    }
  }
}

// ------------------- lag aggregation: agg = sum alpha_i*roll(v) ------------
__global__ __launch_bounds__(256) void agg_kernel(const _Float16* __restrict__ v,
                                                  const int* __restrict__ delays,
                                                  const float* __restrict__ alphas,
                                                  _Float16* __restrict__ agg,
                                                  int L, int C) {
  int bt = blockIdx.x;
  int b = bt >> 11, t = bt & 2047;
  int tid = threadIdx.x;
  const _Float16* vb = v + (size_t)b * L * C;
  float ax = 0.f, ay = 0.f, az = 0.f, aw = 0.f;
#pragma unroll
  for (int i = 0; i < 7; ++i) {
    int d = delays[b * 7 + i];
    float a = alphas[b * 7 + i];
    int src = t + d;
    if (src >= L) src -= L;
    half4 x = ((const half4*)(vb + (size_t)src * C))[tid];
    ax += a * (float)x.x; ay += a * (float)x.y;
    az += a * (float)x.z; aw += a * (float)x.w;
  }
  half4 h = {(_Float16)ax, (_Float16)ay, (_Float16)az, (_Float16)aw};
  ((half4*)(agg + (size_t)bt * C))[tid] = h;
}

// ----------------- series decomposition: out = x - movavg25(x) -------------
// grid (C/256, L/128, B); sliding window with edge-clamped indices
template <int WRITE_H>
__global__ __launch_bounds__(256) void decomp_kernel(const float* __restrict__ xin,
                                                     float* __restrict__ xout,
                                                     _Float16* __restrict__ xh,
                                                     int L, int C) {
  int c = blockIdx.x * 256 + threadIdx.x;
  int t0 = blockIdx.y * 128;
  int b = blockIdx.z;
  const float* xb = xin + (size_t)b * L * C + c;
  float sum = 0.f;
  for (int j = t0 - 12; j <= t0 + 12; ++j) {
    int jc = j < 0 ? 0 : (j > L - 1 ? L - 1 : j);
    sum += xb[(size_t)jc * C];
  }
  for (int t = t0; t < t0 + 128; ++t) {
    float xv = xb[(size_t)t * C];
    float o = xv - sum * (1.0f / 25.0f);
    size_t oidx = ((size_t)b * L + t) * C + c;
    xout[oidx] = o;
    if (WRITE_H) xh[oidx] = (_Float16)o;
    int nj = t + 13; if (nj > L - 1) nj = L - 1;
    int oj = t - 12; if (oj < 0) oj = 0;
    sum += xb[(size_t)nj * C] - xb[(size_t)oj * C];
  }
}

// ------------------------------- launcher ----------------------------------
extern "C" void kernel_launch(void* const* d_in, const int* in_sizes, int n_in,
                              void* d_out, int out_size, void* d_ws, size_t ws_size,
                              hipStream_t stream) {
  const float* x = (const float*)d_in[0];
  const float* Wq = (const float*)d_in[1];
  const float* Wk = (const float*)d_in[2];
  const float* Wv = (const float*)d_in[3];
  const float* Wo = (const float*)d_in[4];
  const float* bo = (const float*)d_in[5];
  const float* lng = (const float*)d_in[6];
  const float* lnb = (const float*)d_in[7];
  const float* W1 = (const float*)d_in[8];
  const float* W2 = (const float*)d_in[9];
  float* out = (float*)d_out;

  const int B = 8, L = 2048, C = 1024, HD = 4096;
  const int M = B * L;  // 16384
  const int MCH = 4096; // FFN row-chunk

  char* ws = (char*)d_ws;
  size_t off = 0;
  auto alloc = [&](size_t bytes) -> void* {
    void* p = ws + off;
    off = (off + bytes + 255) & ~(size_t)255;
    return p;
  };
  // total ws usage: ~152.1 MB
  _Float16* wqh = (_Float16*)alloc((size_t)C * C * 2);     // 2 MB
  _Float16* wkh = (_Float16*)alloc((size_t)C * C * 2);     // 2 MB
  _Float16* wvh = (_Float16*)alloc((size_t)C * C * 2);     // 2 MB
  _Float16* woh = (_Float16*)alloc((size_t)C * C * 2);     // 2 MB
  _Float16* w1h = (_Float16*)alloc((size_t)HD * C * 2);    // 8 MB
  _Float16* w2h = (_Float16*)alloc((size_t)C * HD * 2);    // 8 MB
  float* S = (float*)alloc((size_t)B * 1025 * 2 * 4);      // 64 KB
  int* dl = (int*)alloc(B * 7 * 4);
  float* al = (float*)alloc(B * 7 * 4);
  _Float16* xn = (_Float16*)alloc((size_t)M * C * 2);      // 32 MB; later agg, hid_c
  _Float16* qh = (_Float16*)alloc((size_t)M * C * 2);      // 32 MB  } qh+kh contiguous:
  _Float16* kh = (_Float16*)alloc((size_t)M * C * 2);      // 32 MB  } x1/x3 fp32 (64 MB)
  _Float16* vh = (_Float16*)alloc((size_t)M * C * 2);      // 32 MB; later x2h
  (void)ws_size; (void)in_sizes; (void)n_in; (void)out_size;

  _Float16* aggh = xn;            // xn dead after v GEMM
  float* x1 = (float*)qh;         // q,k dead after corr_fft (64 MB spans qh+kh)
  _Float16* x2h = vh;             // v dead after aggregation
  float* x2 = out;                // d_out doubles as x2 scratch
  float* x3 = (float*)qh;         // x1 dead after decomp1
  _Float16* hidc = xn;            // agg dead after Wo GEMM (4096*4096*2 = 32 MB)

  // 1. zero spectrum accumulator (ws is poisoned before every call)
  zero_kernel<<<(B * 1025 * 2 + 255) / 256, 256, 0, stream>>>(S, B * 1025 * 2);
  // 2. weights -> fp16
  cvt_f16_kernel<<<(C * C / 4 + 255) / 256, 256, 0, stream>>>(Wq, wqh, C * C / 4);
  cvt_f16_kernel<<<(C * C / 4 + 255) / 256, 256, 0, stream>>>(Wk, wkh, C * C / 4);
  cvt_f16_kernel<<<(C * C / 4 + 255) / 256, 256, 0, stream>>>(Wv, wvh, C * C / 4);
  cvt_f16_kernel<<<(C * C / 4 + 255) / 256, 256, 0, stream>>>(Wo, woh, C * C / 4);
  cvt_f16_kernel<<<(HD * C / 4 + 255) / 256, 256, 0, stream>>>(W1, w1h, HD * C / 4);
  cvt_f16_kernel<<<(HD * C / 4 + 255) / 256, 256, 0, stream>>>(W2, w2h, HD * C / 4);
  // 3. LayerNorm -> fp16
  ln_kernel<<<M, 256, 0, stream>>>(x, lng, lnb, xn, C);
  // 4. q,k,v GEMMs (fp16 out)
  dim3 g1(C / 128, M / 128);
  gemm_kernel<4><<<g1, 256, 0, stream>>>(xn, wqh, M, C, C, nullptr, qh, nullptr, nullptr);
  gemm_kernel<4><<<g1, 256, 0, stream>>>(xn, wkh, M, C, C, nullptr, kh, nullptr, nullptr);
  gemm_kernel<4><<<g1, 256, 0, stream>>>(xn, wvh, M, C, C, nullptr, vh, nullptr, nullptr);
  // 5. channel FFTs + spectrum accumulation
  corr_fft_kernel<<<B * (C / 4), 256, 0, stream>>>(qh, kh, S, L, C);
  // 6. inverse FFT + top-7 + softmax
  corr_topk_kernel<<<B, 256, 0, stream>>>(S, dl, al, C, L);
  // 7. lag aggregation -> fp16 (into xn region)
  agg_kernel<<<B * L, 256, 0, stream>>>(vh, dl, al, aggh, L, C);
  // 8. Wo GEMM + bias + residual(x) -> x1 (fp32, qh+kh region)
  gemm_kernel<1><<<g1, 256, 0, stream>>>(aggh, woh, M, C, C, x1, nullptr, bo, x);
  // 9. decomp1: x2 = x1 - movavg(x1) -> d_out (fp32) + fp16 copy in vh
  decomp_kernel<1><<<dim3(C / 256, L / 128, B), 256, 0, stream>>>(x1, x2, x2h, L, C);
  // 10/11. FFN chunked over rows (hid chunk 32 MB in xn region)
  dim3 gf1(HD / 128, MCH / 128);
  dim3 gf2(C / 128, MCH / 128);
  for (int ci = 0; ci < M / MCH; ++ci) {
    size_t ro = (size_t)ci * MCH;
    gemm_kernel<2><<<gf1, 256, 0, stream>>>(x2h + ro * C, w1h, MCH, HD, C,
                                            nullptr, hidc, nullptr, nullptr);
    gemm_kernel<3><<<gf2, 256, 0, stream>>>(hidc, w2h, MCH, C, HD,
                                            x3 + ro * C, nullptr, nullptr, x2 + ro * C);
  }
  // 12. decomp2 -> out
  decomp_kernel<0><<<dim3(C / 256, L / 128, B), 256, 0, stream>>>(x3, out, nullptr, L, C);
}

// Round 3
// 1356.416 us; speedup vs baseline: 2.0623x; 2.0623x over previous
//
#include <hip/hip_runtime.h>
#include <cstdint>
#include <cstddef>

// ---------------------------------------------------------------------------
// AutoformerEncodeBlock: LN -> q,k,v GEMMs -> FFT autocorrelation top-7 lag
// aggregation -> Wo GEMM (+bias+residual) -> decomp1 (x - movavg25) ->
// FFN (GELU) -> residual -> decomp2 -> out.
// B=8 L=2048 C=1024 H=16 D=64 Hd=4096, fp32 in/out, fp16 MFMA for GEMMs.
// R3: global_load_lds(16B) staging (m97 structure), grid x=M for XCD A-reuse,
//     q/k transposed [B,C,L] epilogue -> coalesced corr_fft.
// ---------------------------------------------------------------------------

typedef _Float16 half8 __attribute__((ext_vector_type(8)));
typedef _Float16 half4 __attribute__((ext_vector_type(4)));
typedef float floatx4 __attribute__((ext_vector_type(4)));

#define PI_F 3.14159265358979323846f

__device__ __forceinline__ void load_lds16(const void* g, void* l) {
  __builtin_amdgcn_global_load_lds((__attribute__((address_space(1))) void*)g,
                                   (__attribute__((address_space(3))) void*)l,
                                   16, 0, 0);
}

// ---------------------------- small utility kernels ------------------------

__global__ __launch_bounds__(256) void zero_kernel(float* p, int n) {
  int i = blockIdx.x * 256 + threadIdx.x;
  if (i < n) p[i] = 0.f;
}

__global__ __launch_bounds__(256) void cvt_f16_kernel(const float* __restrict__ src,
                                                      _Float16* __restrict__ dst, int n4) {
  int i = blockIdx.x * 256 + threadIdx.x;
  if (i >= n4) return;
  float4 v = ((const float4*)src)[i];
  half4 h = {(_Float16)v.x, (_Float16)v.y, (_Float16)v.z, (_Float16)v.w};
  ((half4*)dst)[i] = h;
}

// --------------------------------- LayerNorm -------------------------------
__global__ __launch_bounds__(256) void ln_kernel(const float* __restrict__ x,
                                                 const float* __restrict__ g,
                                                 const float* __restrict__ b,
                                                 _Float16* __restrict__ xn, int C) {
  int row = blockIdx.x;
  int t = threadIdx.x;
  const float4* xr = (const float4*)(x + (size_t)row * C);
  float4 v = xr[t];
  float s = v.x + v.y + v.z + v.w;
  float s2 = v.x * v.x + v.y * v.y + v.z * v.z + v.w * v.w;
  for (int o = 32; o > 0; o >>= 1) {
    s += __shfl_down(s, o, 64);
    s2 += __shfl_down(s2, o, 64);
  }
  __shared__ float red[8];
  int wave = t >> 6, lane = t & 63;
  if (lane == 0) { red[wave] = s; red[4 + wave] = s2; }
  __syncthreads();
  __shared__ float stats[2];
  if (t == 0) {
    float ts = red[0] + red[1] + red[2] + red[3];
    float ts2 = red[4] + red[5] + red[6] + red[7];
    float mu = ts / (float)C;
    float var = ts2 / (float)C - mu * mu;
    stats[0] = mu;
    stats[1] = 1.0f / sqrtf(var + 1e-5f);
  }
  __syncthreads();
  float mu = stats[0], rs = stats[1];
  float4 gv = ((const float4*)g)[t];
  float4 bv = ((const float4*)b)[t];
  half4 h = {(_Float16)((v.x - mu) * rs * gv.x + bv.x),
             (_Float16)((v.y - mu) * rs * gv.y + bv.y),
             (_Float16)((v.z - mu) * rs * gv.z + bv.z),
             (_Float16)((v.w - mu) * rs * gv.w + bv.w)};
  ((half4*)(xn + (size_t)row * C))[t] = h;
}

// ----------------------------------- GEMM ----------------------------------
// C[M,N] = A[M,K] * Bw[N,K]^T  (fp16, K-contiguous). 128x128 tile, BK=64,
// 4 waves 2x2, each wave 4x4 of 16x16x32 MFMA. Staging: global_load_lds x16B,
// m97 2-barrier K-loop. Grid: x = M-dim (XCD A-locality), y = N-dim.
// EPI: 1 = +bias[col]+res fp32, 2 = GELU -> fp16, 3 = +res fp32,
//      4 = plain fp16, 5 = fp16 transposed [B,C,L] (L=2048)
template <int EPI>
__global__ __launch_bounds__(256) void gemm_kernel(
    const _Float16* __restrict__ A, const _Float16* __restrict__ Bw,
    int M, int N, int K,
    float* __restrict__ outf, _Float16* __restrict__ outh,
    const float* __restrict__ bias, const float* __restrict__ res) {
  __shared__ _Float16 sA[128 * 64];
  __shared__ _Float16 sB[128 * 64];

  int tid = threadIdx.x;
  int lane = tid & 63;
  int wave = tid >> 6;
  int wm = wave >> 1, wn = wave & 1;
  int ln15 = lane & 15, q4 = lane >> 4;

  size_t m0 = (size_t)blockIdx.x * 128;  // x = M for XCD-local A reuse
  size_t n0 = (size_t)blockIdx.y * 128;

  floatx4 acc[4][4] = {};

  // staging: chunk tid+256*j covers row=(tid>>3)+32*j, 16B col chunk tid&7
  int row0 = tid >> 3;
  int col16 = tid & 7;
  const _Float16* Ab = A + (m0 + row0) * (size_t)K + col16 * 8;
  const _Float16* Bb = Bw + (n0 + row0) * (size_t)K + col16 * 8;
  char* ldsA = (char*)sA + wave * 1024;  // wave-uniform; HW adds lane*16
  char* ldsB = (char*)sB + wave * 1024;

  int nk = K >> 6;
  for (int ks = 0; ks < nk; ++ks) {
    __syncthreads();  // LDS consumed by previous iter
    size_t k0 = (size_t)ks << 6;
#pragma unroll
    for (int j = 0; j < 4; ++j) {
      load_lds16(Ab + k0 + (size_t)(32 * j) * K, ldsA + j * 4096);
      load_lds16(Bb + k0 + (size_t)(32 * j) * K, ldsB + j * 4096);
    }
    __syncthreads();  // vmcnt(0) drain makes staged data visible
#pragma unroll
    for (int kk = 0; kk < 64; kk += 32) {
      half8 af[4], bf[4];
#pragma unroll
      for (int mi = 0; mi < 4; ++mi)
        af[mi] = *(const half8*)(sA + (wm * 64 + mi * 16 + ln15) * 64 + kk + q4 * 8);
#pragma unroll
      for (int ni = 0; ni < 4; ++ni)
        bf[ni] = *(const half8*)(sB + (wn * 64 + ni * 16 + ln15) * 64 + kk + q4 * 8);
#pragma unroll
      for (int mi = 0; mi < 4; ++mi)
#pragma unroll
        for (int ni = 0; ni < 4; ++ni)
          acc[mi][ni] = __builtin_amdgcn_mfma_f32_16x16x32_f16(af[mi], bf[ni], acc[mi][ni], 0, 0, 0);
    }
  }

  // epilogue: D row = q4*4 + r, col = ln15 within each 16x16 tile
#pragma unroll
  for (int mi = 0; mi < 4; ++mi) {
#pragma unroll
    for (int ni = 0; ni < 4; ++ni) {
      floatx4 a4 = acc[mi][ni];
      size_t rowb = m0 + wm * 64 + mi * 16 + q4 * 4;
      size_t col = n0 + wn * 64 + ni * 16 + ln15;
      if (EPI == 5) {
        // transposed [B, C, L]: lane's 4 rows are L-contiguous
        size_t b = rowb >> 11, l0 = rowb & 2047;
        half4 h = {(_Float16)a4[0], (_Float16)a4[1], (_Float16)a4[2], (_Float16)a4[3]};
        *(half4*)(outh + (((size_t)b * N + col) << 11) + l0) = h;
      } else {
#pragma unroll
        for (int r = 0; r < 4; ++r) {
          size_t idx = (rowb + r) * (size_t)N + col;
          float v = a4[r];
          if (EPI == 1) {
            outf[idx] = v + bias[col] + res[idx];
          } else if (EPI == 2) {
            float ge = 0.5f * v * (1.0f + erff(v * 0.70710678118654752f));
            outh[idx] = (_Float16)ge;
          } else if (EPI == 3) {
            outf[idx] = v + res[idx];
          } else {
            outh[idx] = (_Float16)v;
          }
        }
      }
    }
  }
}

// --------------------- autocorrelation: packed FFT + spectrum --------------
// q,k in transposed [B,C,L] layout -> fully coalesced row loads.
// block = (b, 4 channels). z = q + i*k, 2048-pt radix-2 DIF FFT in LDS
// (bit-reversed output), hermitian split, S[b][f] += sum_ch Qf*conj(Kf).
__global__ __launch_bounds__(256) void corr_fft_kernel(const _Float16* __restrict__ qt,
                                                       const _Float16* __restrict__ kt,
                                                       float* __restrict__ S, int C) {
  __shared__ float2 Z[4][2048];  // 64 KB
  int tid = threadIdx.x;
  int b = blockIdx.x >> 8;              // C/4 = 256 channel-groups
  int c0 = (blockIdx.x & 255) << 2;
  const _Float16* qb = qt + ((size_t)(b * C + c0) << 11);
  const _Float16* kb = kt + ((size_t)(b * C + c0) << 11);
#pragma unroll
  for (int ch = 0; ch < 4; ++ch) {
#pragma unroll
    for (int j = 0; j < 8; ++j) {
      int l = j * 256 + tid;  // consecutive lanes -> consecutive halves
      Z[ch][l] = make_float2((float)qb[(ch << 11) + l], (float)kb[(ch << 11) + l]);
    }
  }
  __syncthreads();
  for (int sh = 10; sh >= 0; --sh) {
    int s = 1 << sh;
    for (int i = tid; i < 4 * 1024; i += 256) {
      int ch = i >> 10;
      int j = i & 1023;
      int t = j & (s - 1);
      int i0 = ((j >> sh) << (sh + 1)) | t;
      int i1 = i0 + s;
      float2 a = Z[ch][i0], bb = Z[ch][i1];
      float2 sum = make_float2(a.x + bb.x, a.y + bb.y);
      float2 d = make_float2(a.x - bb.x, a.y - bb.y);
      float ang = -PI_F * (float)t / (float)s;
      float sn, cs;
      __sincosf(ang, &sn, &cs);
      Z[ch][i0] = sum;
      Z[ch][i1] = make_float2(d.x * cs - d.y * sn, d.x * sn + d.y * cs);
    }
    __syncthreads();
  }
  float* Sb = S + (size_t)b * 1025 * 2;
  for (int f = tid; f <= 1024; f += 256) {
    int rf = __brev((unsigned)f) >> 21;
    int rmf = __brev((unsigned)((2048 - f) & 2047)) >> 21;
    float pr = 0.f, pi = 0.f;
#pragma unroll
    for (int ch = 0; ch < 4; ++ch) {
      float2 zf = Z[ch][rf], zm = Z[ch][rmf];
      float Qr = 0.5f * (zf.x + zm.x), Qi = 0.5f * (zf.y - zm.y);
      float Kr = 0.5f * (zf.y + zm.y), Ki = -0.5f * (zf.x - zm.x);
      pr += Qr * Kr + Qi * Ki;
      pi += Qi * Kr - Qr * Ki;
    }
    atomicAdd(&Sb[2 * f], pr);
    atomicAdd(&Sb[2 * f + 1], pi);
  }
}

// --------------- per-batch: inverse FFT -> mean_corr -> top-7 + softmax ----
__global__ __launch_bounds__(256) void corr_topk_kernel(const float* __restrict__ S,
                                                        int* __restrict__ delays,
                                                        float* __restrict__ alphas,
                                                        int C, int L) {
  __shared__ float2 W[2048];
  __shared__ float mc[2048];
  __shared__ float rv[4];
  __shared__ int ri[4];
  __shared__ float swv[7];
  __shared__ int sdi[7];
  int b = blockIdx.x, tid = threadIdx.x;
  const float* Sb = S + (size_t)b * 1025 * 2;
  for (int f = tid; f < 2048; f += 256) {
    if (f <= 1024) W[f] = make_float2(Sb[2 * f], -Sb[2 * f + 1]);
    else           W[f] = make_float2(Sb[2 * (2048 - f)], Sb[2 * (2048 - f) + 1]);
  }
  __syncthreads();
  for (int sh = 10; sh >= 0; --sh) {
    int s = 1 << sh;
    for (int j = tid; j < 1024; j += 256) {
      int t = j & (s - 1);
      int i0 = ((j >> sh) << (sh + 1)) | t;
      int i1 = i0 + s;
      float2 a = W[i0], bb = W[i1];
      float2 sum = make_float2(a.x + bb.x, a.y + bb.y);
      float2 d = make_float2(a.x - bb.x, a.y - bb.y);
      float ang = -PI_F * (float)t / (float)s;
      float sn, cs;
      __sincosf(ang, &sn, &cs);
      W[i0] = sum;
      W[i1] = make_float2(d.x * cs - d.y * sn, d.x * sn + d.y * cs);
    }
    __syncthreads();
  }
  float inv = 1.0f / ((float)C * (float)L);
  for (int t = tid; t < 2048; t += 256) mc[t] = W[__brev((unsigned)t) >> 21].x * inv;
  __syncthreads();
  int wv = tid >> 6, lane = tid & 63;
  for (int it = 0; it < 7; ++it) {
    float bvv = -1e30f;
    int bi = 0;
    for (int e = tid * 8; e < tid * 8 + 8; ++e) {
      float v = mc[e];
      if (v > bvv) { bvv = v; bi = e; }
    }
    for (int o = 32; o > 0; o >>= 1) {
      float ov = __shfl_down(bvv, o, 64);
      int oi = __shfl_down(bi, o, 64);
      if (ov > bvv || (ov == bvv && oi < bi)) { bvv = ov; bi = oi; }
    }
    if (lane == 0) { rv[wv] = bvv; ri[wv] = bi; }
    __syncthreads();
    if (tid == 0) {
      float fv = rv[0];
      int fi = ri[0];
      for (int w2 = 1; w2 < 4; ++w2)
        if (rv[w2] > fv || (rv[w2] == fv && ri[w2] < fi)) { fv = rv[w2]; fi = ri[w2]; }
      swv[it] = fv;
      sdi[it] = fi;
      mc[fi] = -1e30f;
    }
    __syncthreads();
  }
  if (tid == 0) {
    float mx = swv[0];
    for (int i = 1; i < 7; ++i) mx = fmaxf(mx, swv[i]);
    float e[7], s = 0.f;
    for (int i = 0; i < 7; ++i) { e[i] = expf(swv[i] - mx); s += e[i]; }
    for (int i = 0; i < 7; ++i) {
      alphas[b * 7 + i] = e[i] / s;
      delays[b * 7 + i] = sdi[i];
    }
  }
}

// ------------------- lag aggregation: agg = sum alpha_i*roll(v) ------------
__global__ __launch_bounds__(256) void agg_kernel(const _Float16* __restrict__ v,
                                                  const int* __restrict__ delays,
                                                  const float* __restrict__ alphas,
                                                  _Float16* __restrict__ agg,
                                                  int L, int C) {
  int bt = blockIdx.x;
  int b = bt >> 11, t = bt & 2047;
  int tid = threadIdx.x;
  const _Float16* vb = v + (size_t)b * L * C;
  float ax = 0.f, ay = 0.f, az = 0.f, aw = 0.f;
#pragma unroll
  for (int i = 0; i < 7; ++i) {
    int d = delays[b * 7 + i];
    float a = alphas[b * 7 + i];
    int src = t + d;
    if (src >= L) src -= L;
    half4 x = ((const half4*)(vb + (size_t)src * C))[tid];
    ax += a * (float)x.x; ay += a * (float)x.y;
    az += a * (float)x.z; aw += a * (float)x.w;
  }
  half4 h = {(_Float16)ax, (_Float16)ay, (_Float16)az, (_Float16)aw};
  ((half4*)(agg + (size_t)bt * C))[tid] = h;
}

// ----------------- series decomposition: out = x - movavg25(x) -------------
template <int WRITE_H>
__global__ __launch_bounds__(256) void decomp_kernel(const float* __restrict__ xin,
                                                     float* __restrict__ xout,
                                                     _Float16* __restrict__ xh,
                                                     int L, int C) {
  int c = blockIdx.x * 256 + threadIdx.x;
  int t0 = blockIdx.y * 128;
  int b = blockIdx.z;
  const float* xb = xin + (size_t)b * L * C + c;
  float sum = 0.f;
  for (int j = t0 - 12; j <= t0 + 12; ++j) {
    int jc = j < 0 ? 0 : (j > L - 1 ? L - 1 : j);
    sum += xb[(size_t)jc * C];
  }
  for (int t = t0; t < t0 + 128; ++t) {
    float xv = xb[(size_t)t * C];
    float o = xv - sum * (1.0f / 25.0f);
    size_t oidx = ((size_t)b * L + t) * C + c;
    xout[oidx] = o;
    if (WRITE_H) xh[oidx] = (_Float16)o;
    int nj = t + 13; if (nj > L - 1) nj = L - 1;
    int oj = t - 12; if (oj < 0) oj = 0;
    sum += xb[(size_t)nj * C] - xb[(size_t)oj * C];
  }
}

// ------------------------------- launcher ----------------------------------
extern "C" void kernel_launch(void* const* d_in, const int* in_sizes, int n_in,
                              void* d_out, int out_size, void* d_ws, size_t ws_size,
                              hipStream_t stream) {
  const float* x = (const float*)d_in[0];
  const float* Wq = (const float*)d_in[1];
  const float* Wk = (const float*)d_in[2];
  const float* Wv = (const float*)d_in[3];
  const float* Wo = (const float*)d_in[4];
  const float* bo = (const float*)d_in[5];
  const float* lng = (const float*)d_in[6];
  const float* lnb = (const float*)d_in[7];
  const float* W1 = (const float*)d_in[8];
  const float* W2 = (const float*)d_in[9];
  float* out = (float*)d_out;

  const int B = 8, L = 2048, C = 1024, HD = 4096;
  const int M = B * L;  // 16384
  const int MCH = 4096; // FFN row-chunk

  char* ws = (char*)d_ws;
  size_t off = 0;
  auto alloc = [&](size_t bytes) -> void* {
    void* p = ws + off;
    off = (off + bytes + 255) & ~(size_t)255;
    return p;
  };
  // total ws usage: ~152.1 MB
  _Float16* wqh = (_Float16*)alloc((size_t)C * C * 2);     // 2 MB
  _Float16* wkh = (_Float16*)alloc((size_t)C * C * 2);     // 2 MB
  _Float16* wvh = (_Float16*)alloc((size_t)C * C * 2);     // 2 MB
  _Float16* woh = (_Float16*)alloc((size_t)C * C * 2);     // 2 MB
  _Float16* w1h = (_Float16*)alloc((size_t)HD * C * 2);    // 8 MB
  _Float16* w2h = (_Float16*)alloc((size_t)C * HD * 2);    // 8 MB
  float* S = (float*)alloc((size_t)B * 1025 * 2 * 4);      // 64 KB
  int* dl = (int*)alloc(B * 7 * 4);
  float* al = (float*)alloc(B * 7 * 4);
  _Float16* xn = (_Float16*)alloc((size_t)M * C * 2);      // 32 MB; later agg, hid_c
  _Float16* qh = (_Float16*)alloc((size_t)M * C * 2);      // 32 MB (qt [B,C,L])
  _Float16* kh = (_Float16*)alloc((size_t)M * C * 2);      // 32 MB (kt [B,C,L])
  _Float16* vh = (_Float16*)alloc((size_t)M * C * 2);      // 32 MB; later x2h
  (void)ws_size; (void)in_sizes; (void)n_in; (void)out_size;

  _Float16* aggh = xn;            // xn dead after v GEMM
  float* x1 = (float*)qh;         // q,k dead after corr_fft (64 MB spans qh+kh)
  _Float16* x2h = vh;             // v dead after aggregation
  float* x2 = out;                // d_out doubles as x2 scratch
  float* x3 = (float*)qh;         // x1 dead after decomp1
  _Float16* hidc = xn;            // agg dead after Wo GEMM (4096*4096*2 = 32 MB)

  // 1. zero spectrum accumulator (ws is poisoned before every call)
  zero_kernel<<<(B * 1025 * 2 + 255) / 256, 256, 0, stream>>>(S, B * 1025 * 2);
  // 2. weights -> fp16
  cvt_f16_kernel<<<(C * C / 4 + 255) / 256, 256, 0, stream>>>(Wq, wqh, C * C / 4);
  cvt_f16_kernel<<<(C * C / 4 + 255) / 256, 256, 0, stream>>>(Wk, wkh, C * C / 4);
  cvt_f16_kernel<<<(C * C / 4 + 255) / 256, 256, 0, stream>>>(Wv, wvh, C * C / 4);
  cvt_f16_kernel<<<(C * C / 4 + 255) / 256, 256, 0, stream>>>(Wo, woh, C * C / 4);
  cvt_f16_kernel<<<(HD * C / 4 + 255) / 256, 256, 0, stream>>>(W1, w1h, HD * C / 4);
  cvt_f16_kernel<<<(HD * C / 4 + 255) / 256, 256, 0, stream>>>(W2, w2h, HD * C / 4);
  // 3. LayerNorm -> fp16
  ln_kernel<<<M, 256, 0, stream>>>(x, lng, lnb, xn, C);
  // 4. q,k transposed [B,C,L]; v row-major fp16
  dim3 g1(M / 128, C / 128);
  gemm_kernel<5><<<g1, 256, 0, stream>>>(xn, wqh, M, C, C, nullptr, qh, nullptr, nullptr);
  gemm_kernel<5><<<g1, 256, 0, stream>>>(xn, wkh, M, C, C, nullptr, kh, nullptr, nullptr);
  gemm_kernel<4><<<g1, 256, 0, stream>>>(xn, wvh, M, C, C, nullptr, vh, nullptr, nullptr);
  // 5. channel FFTs + spectrum accumulation (coalesced transposed reads)
  corr_fft_kernel<<<B * (C / 4), 256, 0, stream>>>(qh, kh, S, C);
  // 6. inverse FFT + top-7 + softmax
  corr_topk_kernel<<<B, 256, 0, stream>>>(S, dl, al, C, L);
  // 7. lag aggregation -> fp16 (into xn region)
  agg_kernel<<<B * L, 256, 0, stream>>>(vh, dl, al, aggh, L, C);
  // 8. Wo GEMM + bias + residual(x) -> x1 (fp32, qh+kh region)
  gemm_kernel<1><<<g1, 256, 0, stream>>>(aggh, woh, M, C, C, x1, nullptr, bo, x);
  // 9. decomp1: x2 = x1 - movavg(x1) -> d_out (fp32) + fp16 copy in vh
  decomp_kernel<1><<<dim3(C / 256, L / 128, B), 256, 0, stream>>>(x1, x2, x2h, L, C);
  // 10/11. FFN chunked over rows (hid chunk 32 MB in xn region)
  dim3 gf1(MCH / 128, HD / 128);
  dim3 gf2(MCH / 128, C / 128);
  for (int ci = 0; ci < M / MCH; ++ci) {
    size_t ro = (size_t)ci * MCH;
    gemm_kernel<2><<<gf1, 256, 0, stream>>>(x2h + ro * C, w1h, MCH, HD, C,
                                            nullptr, hidc, nullptr, nullptr);
    gemm_kernel<3><<<gf2, 256, 0, stream>>>(hidc, w2h, MCH, C, HD,
                                            x3 + ro * C, nullptr, nullptr, x2 + ro * C);
  }
  // 12. decomp2 -> out
  decomp_kernel<0><<<dim3(C / 256, L / 128, B), 256, 0, stream>>>(x3, out, nullptr, L, C);
}

// Round 5
// 1219.705 us; speedup vs baseline: 2.2935x; 1.1121x over previous
//
#include <hip/hip_runtime.h>
#include <cstdint>
#include <cstddef>

// ---------------------------------------------------------------------------
// AutoformerEncodeBlock R5 (= R4 resubmit, ws trimmed to 150.7 MB):
//  - corr_fft: padded LDS + twiddle table (kill bank conflicts + sincos), 8-way
//    split spectrum atomics
//  - v-GEMM eliminated: agg commutes with channel mixing -> Wvo = Wo*Wv fold
//  - q,k fused into one N=2048 GEMM (transposed [B,2C,L] epilogue)
//  - FFN re-sliced: FFN1 over N, FFN2 K-partials with RMW epilogue
//  - wvT/woh staged inside vh region (dead before vh's first use)
// ---------------------------------------------------------------------------

typedef _Float16 half8 __attribute__((ext_vector_type(8)));
typedef _Float16 half4 __attribute__((ext_vector_type(4)));
typedef float floatx4 __attribute__((ext_vector_type(4)));

#define PI_F 3.14159265358979323846f
#define ZP(i) ((i) + ((i) >> 4))  // pad every 16 complex elements

__device__ __forceinline__ void load_lds16(const void* g, void* l) {
  __builtin_amdgcn_global_load_lds((__attribute__((address_space(1))) void*)g,
                                   (__attribute__((address_space(3))) void*)l,
                                   16, 0, 0);
}

// ---------------------------- small utility kernels ------------------------

__global__ __launch_bounds__(256) void zero_kernel(float* p, int n) {
  int i = blockIdx.x * 256 + threadIdx.x;
  if (i < n) p[i] = 0.f;
}

__global__ __launch_bounds__(256) void cvt_f16_kernel(const float* __restrict__ src,
                                                      _Float16* __restrict__ dst, int n4) {
  int i = blockIdx.x * 256 + threadIdx.x;
  if (i >= n4) return;
  float4 v = ((const float4*)src)[i];
  half4 h = {(_Float16)v.x, (_Float16)v.y, (_Float16)v.z, (_Float16)v.w};
  ((half4*)dst)[i] = h;
}

// dst[c, j] = src[j, c]  (n x n, fp32 -> fp16), 64x64 LDS tiles
__global__ __launch_bounds__(256) void transpose_f16_kernel(const float* __restrict__ src,
                                                            _Float16* __restrict__ dst, int n) {
  __shared__ float tile[64][65];
  int j0 = blockIdx.y * 64, c0 = blockIdx.x * 64;
  int tr = threadIdx.x >> 4;
  int tc = threadIdx.x & 15;
#pragma unroll
  for (int rr = 0; rr < 64; rr += 16) {
    float4 v = *(const float4*)(src + (size_t)(j0 + tr + rr) * n + c0 + tc * 4);
    tile[tr + rr][tc * 4 + 0] = v.x;
    tile[tr + rr][tc * 4 + 1] = v.y;
    tile[tr + rr][tc * 4 + 2] = v.z;
    tile[tr + rr][tc * 4 + 3] = v.w;
  }
  __syncthreads();
#pragma unroll
  for (int rr = 0; rr < 64; rr += 16) {
    int c = tr + rr;
    half4 h = {(_Float16)tile[tc * 4 + 0][c], (_Float16)tile[tc * 4 + 1][c],
               (_Float16)tile[tc * 4 + 2][c], (_Float16)tile[tc * 4 + 3][c]};
    *(half4*)(dst + (size_t)(c0 + c) * n + j0 + tc * 4) = h;
  }
}

// --------------------------------- LayerNorm -------------------------------
__global__ __launch_bounds__(256) void ln_kernel(const float* __restrict__ x,
                                                 const float* __restrict__ g,
                                                 const float* __restrict__ b,
                                                 _Float16* __restrict__ xn, int C) {
  int row = blockIdx.x;
  int t = threadIdx.x;
  const float4* xr = (const float4*)(x + (size_t)row * C);
  float4 v = xr[t];
  float s = v.x + v.y + v.z + v.w;
  float s2 = v.x * v.x + v.y * v.y + v.z * v.z + v.w * v.w;
  for (int o = 32; o > 0; o >>= 1) {
    s += __shfl_down(s, o, 64);
    s2 += __shfl_down(s2, o, 64);
  }
  __shared__ float red[8];
  int wave = t >> 6, lane = t & 63;
  if (lane == 0) { red[wave] = s; red[4 + wave] = s2; }
  __syncthreads();
  __shared__ float stats[2];
  if (t == 0) {
    float ts = red[0] + red[1] + red[2] + red[3];
    float ts2 = red[4] + red[5] + red[6] + red[7];
    float mu = ts / (float)C;
    float var = ts2 / (float)C - mu * mu;
    stats[0] = mu;
    stats[1] = 1.0f / sqrtf(var + 1e-5f);
  }
  __syncthreads();
  float mu = stats[0], rs = stats[1];
  float4 gv = ((const float4*)g)[t];
  float4 bv = ((const float4*)b)[t];
  half4 h = {(_Float16)((v.x - mu) * rs * gv.x + bv.x),
             (_Float16)((v.y - mu) * rs * gv.y + bv.y),
             (_Float16)((v.z - mu) * rs * gv.z + bv.z),
             (_Float16)((v.w - mu) * rs * gv.w + bv.w)};
  ((half4*)(xn + (size_t)row * C))[t] = h;
}

// ----------------------------------- GEMM ----------------------------------
// C[M,N] = A[M,K] * Bw[N,K]^T  (fp16). lda/ldb = row strides (K-dim).
// 128x128 tile, BK=64, 4 waves 2x2, 4x4 of 16x16x32 MFMA, global_load_lds.
// EPI: 1 = +bias[col]+res fp32, 2 = GELU -> fp16, 3 = +res fp32 (RMW ok),
//      4 = plain fp16, 5 = fp16 transposed [B, N, L] (L=2048)
template <int EPI>
__global__ __launch_bounds__(256) void gemm_kernel(
    const _Float16* __restrict__ A, const _Float16* __restrict__ Bw,
    int M, int N, int K, int lda, int ldb,
    float* __restrict__ outf, _Float16* __restrict__ outh,
    const float* __restrict__ bias, const float* __restrict__ res) {
  __shared__ _Float16 sA[128 * 64];
  __shared__ _Float16 sB[128 * 64];

  int tid = threadIdx.x;
  int lane = tid & 63;
  int wave = tid >> 6;
  int wm = wave >> 1, wn = wave & 1;
  int ln15 = lane & 15, q4 = lane >> 4;

  size_t m0 = (size_t)blockIdx.x * 128;  // x = M for XCD-local A reuse
  size_t n0 = (size_t)blockIdx.y * 128;

  floatx4 acc[4][4] = {};

  int row0 = tid >> 3;
  int col16 = tid & 7;
  const _Float16* Ab = A + (m0 + row0) * (size_t)lda + col16 * 8;
  const _Float16* Bb = Bw + (n0 + row0) * (size_t)ldb + col16 * 8;
  char* ldsA = (char*)sA + wave * 1024;  // wave-uniform; HW adds lane*16
  char* ldsB = (char*)sB + wave * 1024;

  int nk = K >> 6;
  for (int ks = 0; ks < nk; ++ks) {
    __syncthreads();
    size_t k0 = (size_t)ks << 6;
#pragma unroll
    for (int j = 0; j < 4; ++j) {
      load_lds16(Ab + k0 + (size_t)(32 * j) * lda, ldsA + j * 4096);
      load_lds16(Bb + k0 + (size_t)(32 * j) * ldb, ldsB + j * 4096);
    }
    __syncthreads();
#pragma unroll
    for (int kk = 0; kk < 64; kk += 32) {
      half8 af[4], bf[4];
#pragma unroll
      for (int mi = 0; mi < 4; ++mi)
        af[mi] = *(const half8*)(sA + (wm * 64 + mi * 16 + ln15) * 64 + kk + q4 * 8);
#pragma unroll
      for (int ni = 0; ni < 4; ++ni)
        bf[ni] = *(const half8*)(sB + (wn * 64 + ni * 16 + ln15) * 64 + kk + q4 * 8);
#pragma unroll
      for (int mi = 0; mi < 4; ++mi)
#pragma unroll
        for (int ni = 0; ni < 4; ++ni)
          acc[mi][ni] = __builtin_amdgcn_mfma_f32_16x16x32_f16(af[mi], bf[ni], acc[mi][ni], 0, 0, 0);
    }
  }

#pragma unroll
  for (int mi = 0; mi < 4; ++mi) {
#pragma unroll
    for (int ni = 0; ni < 4; ++ni) {
      floatx4 a4 = acc[mi][ni];
      size_t rowb = m0 + wm * 64 + mi * 16 + q4 * 4;
      size_t col = n0 + wn * 64 + ni * 16 + ln15;
      if (EPI == 5) {
        size_t b = rowb >> 11, l0 = rowb & 2047;
        half4 h = {(_Float16)a4[0], (_Float16)a4[1], (_Float16)a4[2], (_Float16)a4[3]};
        *(half4*)(outh + (((size_t)b * N + col) << 11) + l0) = h;
      } else {
#pragma unroll
        for (int r = 0; r < 4; ++r) {
          size_t idx = (rowb + r) * (size_t)N + col;
          float v = a4[r];
          if (EPI == 1) {
            outf[idx] = v + bias[col] + res[idx];
          } else if (EPI == 2) {
            float ge = 0.5f * v * (1.0f + erff(v * 0.70710678118654752f));
            outh[idx] = (_Float16)ge;
          } else if (EPI == 3) {
            outf[idx] = v + res[idx];
          } else {
            outh[idx] = (_Float16)v;
          }
        }
      }
    }
  }
}

// --------------------- autocorrelation: packed FFT + spectrum --------------
// qk fused transposed layout F[b, ch, l], ch<1024 = q, ch>=1024 = k.
// block = (b, 4 channel-pairs). z = q + i*k, 2048-pt radix-2 DIF FFT in
// padded LDS with twiddle table; hermitian split; 8-way split atomics.
__global__ __launch_bounds__(256) void corr_fft_kernel(const _Float16* __restrict__ F,
                                                       float* __restrict__ S) {
  __shared__ float2 Z[4][2176];   // 2048 + pad every 16
  __shared__ float2 twl[1088];    // 1024 twiddles, padded
  int tid = threadIdx.x;
  int b = blockIdx.x >> 8;
  int c0 = (blockIdx.x & 255) << 2;
  const _Float16* qb = F + ((size_t)(b * 2048 + c0) << 11);
  const _Float16* kb = F + ((size_t)(b * 2048 + 1024 + c0) << 11);
  // twiddle table: twl[m] = exp(-2*pi*i*m/2048)
  for (int m = tid; m < 1024; m += 256) {
    float sn, cs;
    __sincosf(-PI_F * (float)m / 1024.0f, &sn, &cs);
    twl[ZP(m)] = make_float2(cs, sn);
  }
#pragma unroll
  for (int ch = 0; ch < 4; ++ch) {
#pragma unroll
    for (int j = 0; j < 2; ++j) {
      int l0 = (j * 256 + tid) * 4;
      half4 qv = *(const half4*)(qb + ((size_t)ch << 11) + l0);
      half4 kv = *(const half4*)(kb + ((size_t)ch << 11) + l0);
#pragma unroll
      for (int u = 0; u < 4; ++u)
        Z[ch][ZP(l0 + u)] = make_float2((float)qv[u], (float)kv[u]);
    }
  }
  __syncthreads();
  for (int sh = 10; sh >= 0; --sh) {
    int s = 1 << sh;
    for (int i = tid; i < 4 * 1024; i += 256) {
      int ch = i >> 10;
      int j = i & 1023;
      int t = j & (s - 1);
      int i0 = ((j >> sh) << (sh + 1)) | t;
      int i1 = i0 + s;
      float2 a = Z[ch][ZP(i0)], bb = Z[ch][ZP(i1)];
      float2 w = twl[ZP(t << (10 - sh))];
      float2 d = make_float2(a.x - bb.x, a.y - bb.y);
      Z[ch][ZP(i0)] = make_float2(a.x + bb.x, a.y + bb.y);
      Z[ch][ZP(i1)] = make_float2(d.x * w.x - d.y * w.y, d.x * w.y + d.y * w.x);
    }
    __syncthreads();
  }
  float* Sb = S + ((size_t)b * 8 + (blockIdx.x & 7)) * 2050;
  for (int f = tid; f <= 1024; f += 256) {
    int rf = __brev((unsigned)f) >> 21;
    int rmf = __brev((unsigned)((2048 - f) & 2047)) >> 21;
    float pr = 0.f, pi = 0.f;
#pragma unroll
    for (int ch = 0; ch < 4; ++ch) {
      float2 zf = Z[ch][ZP(rf)], zm = Z[ch][ZP(rmf)];
      float Qr = 0.5f * (zf.x + zm.x), Qi = 0.5f * (zf.y - zm.y);
      float Kr = 0.5f * (zf.y + zm.y), Ki = -0.5f * (zf.x - zm.x);
      pr += Qr * Kr + Qi * Ki;
      pi += Qi * Kr - Qr * Ki;
    }
    atomicAdd(&Sb[2 * f], pr);
    atomicAdd(&Sb[2 * f + 1], pi);
  }
}

// --------------- per-batch: inverse FFT -> mean_corr -> top-7 + softmax ----
__global__ __launch_bounds__(256) void corr_topk_kernel(const float* __restrict__ S,
                                                        int* __restrict__ delays,
                                                        float* __restrict__ alphas,
                                                        int C, int L) {
  __shared__ float2 W[2048];
  __shared__ float mc[2048];
  __shared__ float rv[4];
  __shared__ int ri[4];
  __shared__ float swv[7];
  __shared__ int sdi[7];
  int b = blockIdx.x, tid = threadIdx.x;
  const float* Sb = S + (size_t)b * 8 * 2050;
  for (int f = tid; f < 2048; f += 256) {
    int ff = f <= 1024 ? f : 2048 - f;
    float re = 0.f, im = 0.f;
    for (int s = 0; s < 8; ++s) {
      re += Sb[s * 2050 + 2 * ff];
      im += Sb[s * 2050 + 2 * ff + 1];
    }
    W[f] = make_float2(re, f <= 1024 ? -im : im);
  }
  __syncthreads();
  for (int sh = 10; sh >= 0; --sh) {
    int s = 1 << sh;
    for (int j = tid; j < 1024; j += 256) {
      int t = j & (s - 1);
      int i0 = ((j >> sh) << (sh + 1)) | t;
      int i1 = i0 + s;
      float2 a = W[i0], bb = W[i1];
      float ang = -PI_F * (float)t / (float)s;
      float sn, cs;
      __sincosf(ang, &sn, &cs);
      float2 d = make_float2(a.x - bb.x, a.y - bb.y);
      W[i0] = make_float2(a.x + bb.x, a.y + bb.y);
      W[i1] = make_float2(d.x * cs - d.y * sn, d.x * sn + d.y * cs);
    }
    __syncthreads();
  }
  float inv = 1.0f / ((float)C * (float)L);
  for (int t = tid; t < 2048; t += 256) mc[t] = W[__brev((unsigned)t) >> 21].x * inv;
  __syncthreads();
  int wv = tid >> 6, lane = tid & 63;
  for (int it = 0; it < 7; ++it) {
    float bvv = -1e30f;
    int bi = 0;
    for (int e = tid * 8; e < tid * 8 + 8; ++e) {
      float v = mc[e];
      if (v > bvv) { bvv = v; bi = e; }
    }
    for (int o = 32; o > 0; o >>= 1) {
      float ov = __shfl_down(bvv, o, 64);
      int oi = __shfl_down(bi, o, 64);
      if (ov > bvv || (ov == bvv && oi < bi)) { bvv = ov; bi = oi; }
    }
    if (lane == 0) { rv[wv] = bvv; ri[wv] = bi; }
    __syncthreads();
    if (tid == 0) {
      float fv = rv[0];
      int fi = ri[0];
      for (int w2 = 1; w2 < 4; ++w2)
        if (rv[w2] > fv || (rv[w2] == fv && ri[w2] < fi)) { fv = rv[w2]; fi = ri[w2]; }
      swv[it] = fv;
      sdi[it] = fi;
      mc[fi] = -1e30f;
    }
    __syncthreads();
  }
  if (tid == 0) {
    float mx = swv[0];
    for (int i = 1; i < 7; ++i) mx = fmaxf(mx, swv[i]);
    float e[7], s = 0.f;
    for (int i = 0; i < 7; ++i) { e[i] = expf(swv[i] - mx); s += e[i]; }
    for (int i = 0; i < 7; ++i) {
      alphas[b * 7 + i] = e[i] / s;
      delays[b * 7 + i] = sdi[i];
    }
  }
}

// ------------------- lag aggregation on xn (commuted past Wv) --------------
__global__ __launch_bounds__(256) void agg_kernel(const _Float16* __restrict__ v,
                                                  const int* __restrict__ delays,
                                                  const float* __restrict__ alphas,
                                                  _Float16* __restrict__ agg,
                                                  int L, int C) {
  int bt = blockIdx.x;
  int b = bt >> 11, t = bt & 2047;
  int tid = threadIdx.x;
  const _Float16* vb = v + (size_t)b * L * C;
  float ax = 0.f, ay = 0.f, az = 0.f, aw = 0.f;
#pragma unroll
  for (int i = 0; i < 7; ++i) {
    int d = delays[b * 7 + i];
    float a = alphas[b * 7 + i];
    int src = t + d;
    if (src >= L) src -= L;
    half4 x = ((const half4*)(vb + (size_t)src * C))[tid];
    ax += a * (float)x.x; ay += a * (float)x.y;
    az += a * (float)x.z; aw += a * (float)x.w;
  }
  half4 h = {(_Float16)ax, (_Float16)ay, (_Float16)az, (_Float16)aw};
  ((half4*)(agg + (size_t)bt * C))[tid] = h;
}

// ----------------- series decomposition: out = x - movavg25(x) -------------
template <int WRITE_H>
__global__ __launch_bounds__(256) void decomp_kernel(const float* __restrict__ xin,
                                                     float* __restrict__ xout,
                                                     _Float16* __restrict__ xh,
                                                     int L, int C) {
  int c = blockIdx.x * 256 + threadIdx.x;
  int t0 = blockIdx.y * 128;
  int b = blockIdx.z;
  const float* xb = xin + (size_t)b * L * C + c;
  float sum = 0.f;
  for (int j = t0 - 12; j <= t0 + 12; ++j) {
    int jc = j < 0 ? 0 : (j > L - 1 ? L - 1 : j);
    sum += xb[(size_t)jc * C];
  }
  for (int t = t0; t < t0 + 128; ++t) {
    float xv = xb[(size_t)t * C];
    float o = xv - sum * (1.0f / 25.0f);
    size_t oidx = ((size_t)b * L + t) * C + c;
    xout[oidx] = o;
    if (WRITE_H) xh[oidx] = (_Float16)o;
    int nj = t + 13; if (nj > L - 1) nj = L - 1;
    int oj = t - 12; if (oj < 0) oj = 0;
    sum += xb[(size_t)nj * C] - xb[(size_t)oj * C];
  }
}

// ------------------------------- launcher ----------------------------------
extern "C" void kernel_launch(void* const* d_in, const int* in_sizes, int n_in,
                              void* d_out, int out_size, void* d_ws, size_t ws_size,
                              hipStream_t stream) {
  const float* x = (const float*)d_in[0];
  const float* Wq = (const float*)d_in[1];
  const float* Wk = (const float*)d_in[2];
  const float* Wv = (const float*)d_in[3];
  const float* Wo = (const float*)d_in[4];
  const float* bo = (const float*)d_in[5];
  const float* lng = (const float*)d_in[6];
  const float* lnb = (const float*)d_in[7];
  const float* W1 = (const float*)d_in[8];
  const float* W2 = (const float*)d_in[9];
  float* out = (float*)d_out;

  const int B = 8, L = 2048, C = 1024, HD = 4096;
  const int M = B * L;  // 16384

  char* ws = (char*)d_ws;
  size_t off = 0;
  auto alloc = [&](size_t bytes) -> void* {
    void* p = ws + off;
    off = (off + bytes + 255) & ~(size_t)255;
    return p;
  };
  // ~150.7 MB total (under the 152.1 MB proven in R2/R3)
  _Float16* wqkh = (_Float16*)alloc((size_t)2 * C * C * 2); // 4 MB (q rows, then k rows)
  _Float16* wvoh = (_Float16*)alloc((size_t)C * C * 2);     // 2 MB (Wo*Wv)
  _Float16* w1h = (_Float16*)alloc((size_t)HD * C * 2);     // 8 MB
  _Float16* w2h = (_Float16*)alloc((size_t)C * HD * 2);     // 8 MB
  float* S = (float*)alloc((size_t)B * 8 * 2050 * 4);       // 512 KB (8-way split)
  int* dl = (int*)alloc(B * 7 * 4);
  float* al = (float*)alloc(B * 7 * 4);
  _Float16* xn = (_Float16*)alloc((size_t)M * C * 2);       // 32 MB; later x2h
  _Float16* qkh = (_Float16*)alloc((size_t)M * 2 * C * 2);  // 64 MB [B,2C,L]; later x1/x3
  _Float16* vh = (_Float16*)alloc((size_t)M * C * 2);       // 32 MB: wvT/woh setup, aggh, hid
  (void)ws_size; (void)in_sizes; (void)n_in; (void)out_size;

  _Float16* wvT = vh;                        // setup-only (dead before step 8)
  _Float16* woh = vh + (size_t)C * C;        // setup-only (dead before step 8)
  _Float16* aggh = vh;            // agg of xn (from step 8)
  float* x1 = (float*)qkh;        // q,k dead after corr_fft (64 MB)
  _Float16* x2h = xn;             // xn dead after agg
  float* x2 = out;                // d_out doubles as x2 scratch
  float* x3 = (float*)qkh;        // x1 dead after decomp1
  _Float16* hidc = vh;            // aggh dead after attn GEMM (32 MB slice)

  // 1. zero spectrum accumulator
  zero_kernel<<<(B * 8 * 2050 + 255) / 256, 256, 0, stream>>>(S, B * 8 * 2050);
  // 2. weights -> fp16 (+ Wv transpose)
  cvt_f16_kernel<<<(C * C / 4 + 255) / 256, 256, 0, stream>>>(Wq, wqkh, C * C / 4);
  cvt_f16_kernel<<<(C * C / 4 + 255) / 256, 256, 0, stream>>>(Wk, wqkh + (size_t)C * C, C * C / 4);
  cvt_f16_kernel<<<(C * C / 4 + 255) / 256, 256, 0, stream>>>(Wo, woh, C * C / 4);
  transpose_f16_kernel<<<dim3(16, 16), 256, 0, stream>>>(Wv, wvT, C);
  cvt_f16_kernel<<<(HD * C / 4 + 255) / 256, 256, 0, stream>>>(W1, w1h, HD * C / 4);
  cvt_f16_kernel<<<(HD * C / 4 + 255) / 256, 256, 0, stream>>>(W2, w2h, HD * C / 4);
  // 3. Wvo[o,c] = sum_j Wo[o,j]*Wv[j,c]
  gemm_kernel<4><<<dim3(8, 8), 256, 0, stream>>>(woh, wvT, C, C, C, C, C,
                                                 nullptr, wvoh, nullptr, nullptr);
  // 4. LayerNorm -> fp16
  ln_kernel<<<M, 256, 0, stream>>>(x, lng, lnb, xn, C);
  // 5. fused q,k GEMM -> transposed [B, 2C, L]
  gemm_kernel<5><<<dim3(M / 128, 2 * C / 128), 256, 0, stream>>>(
      xn, wqkh, M, 2 * C, C, C, C, nullptr, qkh, nullptr, nullptr);
  // 6. channel FFTs + spectrum accumulation
  corr_fft_kernel<<<B * (C / 4), 256, 0, stream>>>(qkh, S);
  // 7. inverse FFT + top-7 + softmax
  corr_topk_kernel<<<B, 256, 0, stream>>>(S, dl, al, C, L);
  // 8. lag aggregation on xn (commuted) -> aggh
  agg_kernel<<<B * L, 256, 0, stream>>>(xn, dl, al, aggh, L, C);
  // 9. attn = aggh * Wvo^T + bo + x -> x1 (fp32)
  gemm_kernel<1><<<dim3(M / 128, C / 128), 256, 0, stream>>>(
      aggh, wvoh, M, C, C, C, C, x1, nullptr, bo, x);
  // 10. decomp1: x2 = x1 - movavg(x1) -> d_out + fp16 copy (xn region)
  decomp_kernel<1><<<dim3(C / 256, L / 128, B), 256, 0, stream>>>(x1, x2, x2h, L, C);
  // 11. FFN: N-sliced FFN1, K-partial FFN2 (1024-block dispatches)
  for (int ci = 0; ci < 4; ++ci) {
    gemm_kernel<2><<<dim3(M / 128, 8), 256, 0, stream>>>(
        x2h, w1h + (size_t)ci * 1024 * C, M, 1024, C, C, C,
        nullptr, hidc, nullptr, nullptr);
    gemm_kernel<3><<<dim3(M / 128, C / 128), 256, 0, stream>>>(
        hidc, w2h + (size_t)ci * 1024, M, C, 1024, 1024, HD,
        x3, nullptr, nullptr, ci == 0 ? x2 : x3);
  }
  // 12. decomp2 -> out
  decomp_kernel<0><<<dim3(C / 256, L / 128, B), 256, 0, stream>>>(x3, out, nullptr, L, C);
}